// Round 1
// baseline (1327.478 us; speedup 1.0000x reference)
//
#include <hip/hip_runtime.h>
#include <cstddef>

// ---------------------------------------------------------------------------
// SNN forward, feed-forward pipeline. CORRECTNESS CONTRACT: reproduce R3's
// sequential-in-ascending-j fp32 fmaf chain per (t,b,o) (passed, 1.5e-5).
// R10 FACT: fmaf(+0, w, acc) == acc EXACTLY (acc never -0), so skipping
// zero-spike j's is bit-identical.
//
// R13 (1130us): ping-pong x2, unconditional W loads, VALUBusy 55%, occ 27%.
// R14 theory: wall fits BOTH (a) per-CU SALU saturation (3 SALU/t gate x 8
// waves ~= 1.8x oversubscribed -> predicted VALUBusy 0.53 ~= measured) and
// (b) depth-1 W-prefetch latency exposure on inactive-j bursts. This round
// attacks both WITHOUT changing NAO/WPB (fewer o/lane would DOUBLE SALU per
// (b,act-j) -> poison under (a)):
//   1) gate = (w & (1u<<t)) ? scale : 0  -> s_and+s_cselect (2 SALU/t, was 3)
//   2) mask windows: 1 coalesced VMEM per 64 j (word per lane), prefetched a
//      full window ahead; per-j word via v_readlane (VALU). No uint4 loads.
//   3) W prefetch depth-2: 4 rotating buffers, 4-group inner step, no copies.
//   4) no min() caps on prefetch (<=8-row overrun stays inside WT/em ws).
// acc static-indexed (R4/R5/R7); ~220 unified regs -> 2 waves/SIMD (kept).
// ---------------------------------------------------------------------------

#define THREADS 256

// WT offsets (floats): WT1[2048][512], WT2[512][512], WT3[512][256],
// WT4[256][128] (w4 zero-padded 100->128 cols)
#define WOFF1 0
#define WOFF2 1048576
#define WOFF3 1310720
#define WOFF4 1441792
#define WTOT  1474560

__global__ __launch_bounds__(THREADS) void prep_kernel(
    const float* __restrict__ w1, const float* __restrict__ w2,
    const float* __restrict__ w3, const float* __restrict__ w4,
    float* __restrict__ wt)
{
  int idx = blockIdx.x * THREADS + threadIdx.x;
  if (idx >= WTOT) return;
  if (idx < WOFF2) {
    int j = idx >> 9, o = idx & 511;
    wt[idx] = w1[o * 2048 + j];
  } else if (idx < WOFF3) {
    int r = idx - WOFF2, j = r >> 9, o = r & 511;
    wt[idx] = w2[o * 512 + j];
  } else if (idx < WOFF4) {
    int r = idx - WOFF3, j = r >> 8, o = r & 255;
    wt[idx] = w3[o * 512 + j];
  } else {
    int r = idx - WOFF4, j = r >> 7, o = r & 127;
    wt[idx] = (o < 100) ? w4[o * 256 + j] : 0.0f;
  }
}

// Encoder (verbatim R3 arithmetic); writes em[b][j] word = bits over t.
__global__ __launch_bounds__(THREADS) void enc_kernel(
    const float* __restrict__ x, const float* __restrict__ fscale,
    unsigned* __restrict__ em, int b0)
{
  int idx = blockIdx.x * THREADS + threadIdx.x;
  int b = idx >> 11, j = idx & 2047;
  float c = 2.0f * fscale[0] * x[((size_t)(b0 + b) << 11) + j];
  float v = 0.0f;
  unsigned m = 0u;
#pragma unroll
  for (int t = 0; t < 32; ++t) {
    v = v + 0.1f * (c - v);
    unsigned z = ((v - 0.33f) > 0.0f) ? 1u : 0u;
    m |= z << t;
    if (z) v = 0.0f;
  }
  em[idx] = m;
}

// ---------------------------------------------------------------------------
// Sparse-j fused GEMM(+LIF / +LI readout), LDS-free, depth-2 pipelined.
//   mIn: em-format masks [b][J], word = bits over t (wave-uniform per j)
//   WT:  [j][o] pre-transposed weights (rows L2-resident)
// Block: 4 waves; wave = (b, o-slice); lane owns NAO consecutive o's,
// acc[32][NAO] holds all t. Masks: one word-per-lane window load per 64 j,
// consumed via v_readlane. W rows: unconditional depth-2 prefetch through
// 4 rotating float4 buffers. FMA bodies conditional (the sparsity win).
// ---------------------------------------------------------------------------
template <int O, bool FINAL>
__global__ __launch_bounds__(THREADS, 2) void gemm_sparse(
    const unsigned* __restrict__ mIn, const float* __restrict__ WT,
    int J, const float* __restrict__ es,
    unsigned* __restrict__ mOut, float* __restrict__ out, int bbase)
{
  constexpr int NAO = (O >= 256) ? 4 : 2;    // o's per lane
  constexpr int WPB = O / (64 * NAO);        // waves per b
  constexpr int BPB = 4 / WPB;               // b's per block
  typedef float fv __attribute__((ext_vector_type(NAO)));
  const int tid = threadIdx.x;
  const int lane = tid & 63, wvid = tid >> 6;
  const int b = blockIdx.x * BPB + wvid / WPB;
  const int obase = (wvid % WPB) * (64 * NAO) + lane * NAO;
  const float* const wbase = WT + obase;     // row j at wbase + j*O
  float scalef = es ? 5.0f * es[0] : 1.0f;   // same expr as R3
  const int scale_i =
      __builtin_amdgcn_readfirstlane(__float_as_int(scalef));

  float acc[32][NAO];
#pragma unroll
  for (int t = 0; t < 32; ++t)
#pragma unroll
    for (int k = 0; k < NAO; ++k) acc[t][k] = 0.0f;

  const unsigned* mrow = mIn + (size_t)b * J;
  const int NW = J >> 6;                     // 64-j mask windows (32/8/8/4)

  auto wloadU = [&](int g, fv* wv) {         // UNCONDITIONAL: no branches,
#pragma unroll                               // no mask dependency
    for (int jj = 0; jj < 4; ++jj)
      wv[jj] = *(const fv*)(wbase + (size_t)(g * 4 + jj) * O);
  };
  auto fma_group = [&](unsigned mw, int q, const fv* wv) {
#pragma unroll
    for (int jj = 0; jj < 4; ++jj) {
      unsigned w = (unsigned)__builtin_amdgcn_readlane((int)mw, q * 4 + jj);
      if (w) {                               // wave-uniform scalar branch
#pragma unroll
        for (int t = 0; t < 32; ++t) {
          // av = bit(w,t) ? scale : 0 — s_and(lit)+s_cselect, SGPR fmaf op
          float av = (w & (1u << t)) ? __int_as_float(scale_i) : 0.0f;
#pragma unroll
          for (int k = 0; k < NAO; ++k)
            acc[t][k] = fmaf(av, wv[jj][k], acc[t][k]);
        }
      }
    }
  };

  // depth-2 W pipeline over 4 buffers; masks one full window ahead.
  fv wvA[4], wvB[4], wvC[4], wvD[4];
  unsigned mwC = mrow[lane];                 // window 0: word per lane
  wloadU(0, wvA);
  wloadU(1, wvB);
#pragma unroll 1
  for (int w = 0; w < NW; ++w) {
    // prefetch next mask window (last window: benign same-row reload)
    unsigned mwN = mrow[((w + 1 < NW) ? (w + 1) << 6 : w << 6) + lane];
    const int gb = w << 4;                   // 16 groups per window
#pragma unroll 1
    for (int q = 0; q < 16; q += 4) {
      const int g = gb + q;
      wloadU(g + 2, wvC);                    // lands 2 groups before use
      fma_group(mwC, q + 0, wvA);
      wloadU(g + 3, wvD);
      fma_group(mwC, q + 1, wvB);
      wloadU(g + 4, wvA);                    // next iter's first buffer
      fma_group(mwC, q + 2, wvC);
      wloadU(g + 5, wvB);                    // (tail overrun <=8 rows: safe,
      fma_group(mwC, q + 3, wvD);            //  in-ws bytes, never consumed)
    }
    mwC = mwN;
  }

  // ---- epilogue: all in registers (t lives in the lane), no barriers ----
#pragma unroll
  for (int k = 0; k < NAO; ++k) {
    if (FINAL) {
      float v = 0.0f, cur = 0.0f;
#pragma unroll
      for (int t2 = 0; t2 < 32; ++t2) {      // verbatim R3 out_li
        v = v + 0.1f * (cur - v);
        cur = 0.8f * cur + acc[t2][k];
      }
      int o = obase + k;
      if (o < 100) out[(size_t)(bbase + b) * 100 + o] = v;
    } else {
      float v = 0.0f, cur = 0.0f;
      unsigned zw = 0u;
#pragma unroll
      for (int t2 = 0; t2 < 32; ++t2) {      // verbatim R3 lif_int
        v = v + 0.1f * (cur - v);
        unsigned z = ((v - 0.33f) > 0.0f) ? 1u : 0u;
        zw |= z << t2;
        if (z) v = 0.0f;
        cur = 0.8f * cur + acc[t2][k];
      }
      mOut[(size_t)b * O + obase + k] = zw;  // em-format for next layer
    }
  }
}

extern "C" void kernel_launch(void* const* d_in, const int* in_sizes, int n_in,
                              void* d_out, int out_size, void* d_ws, size_t ws_size,
                              hipStream_t stream)
{
  const float* x  = (const float*)d_in[0];
  const float* w1 = (const float*)d_in[1];
  const float* w2 = (const float*)d_in[2];
  const float* w3 = (const float*)d_in[3];
  const float* w4 = (const float*)d_in[4];
  const float* fs = (const float*)d_in[5];
  const float* es = (const float*)d_in[6];
  float* out = (float*)d_out;
  (void)in_sizes; (void)n_in; (void)out_size;

  // ws: WT (5.9 MB) + em + s1m + s2m + s3m (all em-format words)
  int Bc = 2048;
  auto need = [](int bc) -> size_t {
    return ((size_t)WTOT + (size_t)bc * (2048 + 512 + 512 + 256)) * 4;
  };
  while (Bc > 64 && need(Bc) > ws_size) Bc >>= 1;

  float* WT = (float*)d_ws;
  unsigned* em  = (unsigned*)(WT + WTOT);
  unsigned* s1m = em  + (size_t)Bc * 2048;
  unsigned* s2m = s1m + (size_t)Bc * 512;
  unsigned* s3m = s2m + (size_t)Bc * 512;

  prep_kernel<<<(WTOT + THREADS - 1) / THREADS, THREADS, 0, stream>>>(
      w1, w2, w3, w4, WT);

  for (int b0 = 0; b0 < 2048; b0 += Bc) {
    enc_kernel<<<(Bc * 2048) / THREADS, THREADS, 0, stream>>>(x, fs, em, b0);
    // L1: J=2048 -> O=512, scale = 5*encoder_scalar
    gemm_sparse<512, false><<<Bc / 2, THREADS, 0, stream>>>(
        em, WT + WOFF1, 2048, es, s1m, nullptr, 0);
    // L2: J=512 -> O=512
    gemm_sparse<512, false><<<Bc / 2, THREADS, 0, stream>>>(
        s1m, WT + WOFF2, 512, nullptr, s2m, nullptr, 0);
    // L3: J=512 -> O=256
    gemm_sparse<256, false><<<Bc / 4, THREADS, 0, stream>>>(
        s2m, WT + WOFF3, 512, nullptr, s3m, nullptr, 0);
    // L4 (readout): J=256 -> O=128 (padded), LI epilogue -> out
    gemm_sparse<128, true><<<Bc / 4, THREADS, 0, stream>>>(
        s3m, WT + WOFF4, 256, nullptr, nullptr, out, b0);
  }
}